// Round 6
// baseline (906.018 us; speedup 1.0000x reference)
//
#include <hip/hip_runtime.h>
#include <stdint.h>

typedef __attribute__((ext_vector_type(8))) short bf16x8;
typedef __attribute__((ext_vector_type(8))) unsigned short u16x8;
typedef __attribute__((ext_vector_type(16))) float f32x16;
typedef __attribute__((ext_vector_type(4))) int i32x4;

static constexpr int MDIM = 8192;   // B*S
static constexpr int KDIM = 4096;   // I
static constexpr int NDIM = 11008;  // O
static constexpr int BM = 256, BN = 256, BK = 32;
static constexpr int NBX = NDIM / BN;  // 43
static constexpr int NBY = MDIM / BM;  // 32

// ---------------- prep: fused A-convert + W-dequant (verified R1/R2/R5) ----------------

static __device__ __forceinline__ unsigned short f2bf(float f) {
  unsigned int u = __builtin_bit_cast(unsigned int, f);
  return (unsigned short)((u + 0x7FFFu + ((u >> 16) & 1u)) >> 16);
}

static __device__ __forceinline__ float fp4_val(unsigned int c) {
  unsigned int m = c & 1u, e = (c >> 1) & 3u, s = (c >> 3) & 1u;
  unsigned int bits = e ? (((126u + e) << 23) | (m << 22)) : (m ? 0x3F000000u : 0u);
  bits |= s << 31;
  return __builtin_bit_cast(float, bits);
}

static constexpr int CONV_BLOCKS = (MDIM * KDIM / 8) / 256;     // 16384
static constexpr int DEQ_BLOCKS  = (NDIM * (KDIM / 32)) / 256;  // 5504

__global__ __launch_bounds__(256) void prep_kernel(
    const float4* __restrict__ in, u16x8* __restrict__ aout,
    const int* __restrict__ pw, const int* __restrict__ sc,
    unsigned short* __restrict__ wout) {
  if (blockIdx.x < CONV_BLOCKS) {
    int i = blockIdx.x * 256 + threadIdx.x;
    float4 v0 = in[2 * (size_t)i];
    float4 v1 = in[2 * (size_t)i + 1];
    u16x8 r;
    r[0] = f2bf(v0.x); r[1] = f2bf(v0.y); r[2] = f2bf(v0.z); r[3] = f2bf(v0.w);
    r[4] = f2bf(v1.x); r[5] = f2bf(v1.y); r[6] = f2bf(v1.z); r[7] = f2bf(v1.w);
    aout[i] = r;
  } else {
    int tid = (blockIdx.x - CONV_BLOCKS) * 256 + threadIdx.x;
    int o = tid >> 7;
    int b = tid & 127;
    const i32x4* src = (const i32x4*)(pw + (size_t)o * (KDIM / 2) + b * 16);
    unsigned int e = (unsigned int)sc[(size_t)o * (KDIM / 32) + b];
    float scale = __builtin_bit_cast(float, e << 23);
    unsigned short* dst = wout + (size_t)o * KDIM + b * 32;
#pragma unroll
    for (int v = 0; v < 4; ++v) {
      i32x4 w4 = src[v];
      u16x8 r;
#pragma unroll
      for (int j = 0; j < 4; ++j) {
        unsigned int w = (unsigned int)w4[j];
        r[2 * j]     = f2bf(fp4_val(w & 0xFu) * scale);
        r[2 * j + 1] = f2bf(fp4_val((w >> 4) & 0xFu) * scale);
      }
      *(u16x8*)(dst + 8 * v) = r;
    }
  }
}

// ------- GEMM: 256x256, BK=32, 32x32x16 MFMA, 4-slot ring (3 ahead), 1 barrier/tile -------

#define GLDS16(gp, lp)                                                                  \
  __builtin_amdgcn_global_load_lds((const __attribute__((address_space(1))) void*)(gp), \
                                   (__attribute__((address_space(3))) void*)(lp), 16, 0, 0)

#define BAR() asm volatile("s_barrier" ::: "memory")

// One K-tile, slot = SLOT; stages tile (t+3) into slot (SLOT+3)&3.
// vmcnt ledger (4 loads/tile): entering tile t outstanding = {t,t+1,t+2} = 12;
// vmcnt(8) completes t's 4. Tail (no stage): t=125 -> 8, t=126 -> 4, t=127 -> 0.
template <int SLOT, bool STAGE, int VN>
__device__ __forceinline__ void ktile(
    unsigned char* lds, const unsigned short*& gA, const unsigned short*& gB,
    int stq, int aBase, int bBase, int kof0, int kof1, f32x16 (&acc)[4][2]) {
  if constexpr (VN == 8)      asm volatile("s_waitcnt vmcnt(8)" ::: "memory");
  else if constexpr (VN == 4) asm volatile("s_waitcnt vmcnt(4)" ::: "memory");
  else                        asm volatile("s_waitcnt vmcnt(0)" ::: "memory");
  BAR();
  if (STAGE) {
    unsigned char* da = lds + ((SLOT + 3) & 3) * 32768 + stq;
    GLDS16(gA, da);
    GLDS16(gA + (size_t)128 * KDIM, da + 8192);
    GLDS16(gB, da + 16384);
    GLDS16(gB + (size_t)128 * KDIM, da + 24576);
    gA += BK; gB += BK;
  }
  const unsigned char* sa = lds + SLOT * 32768;
  const unsigned char* sb = sa + 16384;
  bf16x8 a[4], b[2];
  // cluster ks=0
#pragma unroll
  for (int mf = 0; mf < 4; ++mf) a[mf] = *(const bf16x8*)(sa + aBase + mf * 2048 + kof0);
#pragma unroll
  for (int nf = 0; nf < 2; ++nf) b[nf] = *(const bf16x8*)(sb + bBase + nf * 2048 + kof0);
  __builtin_amdgcn_s_setprio(1);
#pragma unroll
  for (int mf = 0; mf < 4; ++mf)
#pragma unroll
    for (int nf = 0; nf < 2; ++nf)
      acc[mf][nf] = __builtin_amdgcn_mfma_f32_32x32x16_bf16(a[mf], b[nf], acc[mf][nf], 0, 0, 0);
  __builtin_amdgcn_s_setprio(0);
  // cluster ks=1
#pragma unroll
  for (int mf = 0; mf < 4; ++mf) a[mf] = *(const bf16x8*)(sa + aBase + mf * 2048 + kof1);
#pragma unroll
  for (int nf = 0; nf < 2; ++nf) b[nf] = *(const bf16x8*)(sb + bBase + nf * 2048 + kof1);
  __builtin_amdgcn_s_setprio(1);
#pragma unroll
  for (int mf = 0; mf < 4; ++mf)
#pragma unroll
    for (int nf = 0; nf < 2; ++nf)
      acc[mf][nf] = __builtin_amdgcn_mfma_f32_32x32x16_bf16(a[mf], b[nf], acc[mf][nf], 0, 0, 0);
  __builtin_amdgcn_s_setprio(0);
}

__global__ __launch_bounds__(512, 2) void gemm_mx_kernel(
    const unsigned short* __restrict__ A,   // [MDIM][KDIM] bf16
    const unsigned short* __restrict__ Bw,  // [NDIM][KDIM] bf16
    const float* __restrict__ bias,
    float* __restrict__ C) {
  __shared__ __align__(16) unsigned char lds[4 * 32768];  // 128 KiB: 4 x (A16K + B16K)

  const int t = threadIdx.x;
  const int lane = t & 63;
  const int wave = t >> 6;
  const int wr = wave >> 2;  // 0..1 (M)
  const int wc = wave & 3;   // 0..3 (N)

  // bijective XCD swizzle (grid 1376 % 8 == 0)
  const int bid = blockIdx.x;
  const int swb = (bid & 7) * ((NBX * NBY) / 8) + (bid >> 3);
  const int by = swb / NBX;
  const int bx = swb - by * NBX;
  const int m0 = by * BM, n0 = bx * BN;

  // 32x32x16 fragments: lane l holds row (l&31), k = (l>>5)*8 + r   (analog of the
  // R1/R2-verified 16x16x32 mapping row=l&15, k=(l>>4)*8+r).
  const int rl = lane & 31;
  const int hi = lane >> 5;
  // rows are 64 B (4 x 16B granules); swizzle: granule' = (2*ks + hi) ^ (row&3).
  const int kof0 = ((2 * 0 + hi) ^ (rl & 3)) * 16;
  const int kof1 = ((2 * 1 + hi) ^ (rl & 3)) * 16;
  const int aBase = (wr * 128 + rl) * 64;  // frag stride mf: 32 rows = 2048 B
  const int bBase = (wc * 64 + rl) * 64;   // frag stride nf: 32 rows = 2048 B

  // staging: LDS linear; inverse swizzle (same XOR) pre-applied to global column.
  // thread t writes LDS row (t>>2), granule (t&3) of a 128-row x 64B region;
  // source granule = (t&3) ^ (row&3).
  const int stq = t * 16;
  const int srow = t >> 2;                      // 0..127
  const int koff = 8 * ((t & 3) ^ (srow & 3));  // element offset within row
  const unsigned short* gA = A + (size_t)(m0 + srow) * KDIM + koff;
  const unsigned short* gB = Bw + (size_t)(n0 + srow) * KDIM + koff;

  f32x16 acc[4][2] = {};

  // prologue: stage tiles 0,1,2 into slots 0,1,2 (12 loads in flight)
#pragma unroll
  for (int p = 0; p < 3; ++p) {
    unsigned char* da = lds + p * 32768 + stq;
    GLDS16(gA, da);
    GLDS16(gA + (size_t)128 * KDIM, da + 8192);
    GLDS16(gB, da + 16384);
    GLDS16(gB + (size_t)128 * KDIM, da + 24576);
    gA += BK; gB += BK;
  }

  // tiles 0..123 (31 x 4, all staging), 124 (stages 127), 125..127 (drain tail)
  for (int it = 0; it < 31; ++it) {
    ktile<0, true, 8>(lds, gA, gB, stq, aBase, bBase, kof0, kof1, acc);
    ktile<1, true, 8>(lds, gA, gB, stq, aBase, bBase, kof0, kof1, acc);
    ktile<2, true, 8>(lds, gA, gB, stq, aBase, bBase, kof0, kof1, acc);
    ktile<3, true, 8>(lds, gA, gB, stq, aBase, bBase, kof0, kof1, acc);
  }
  ktile<0, true, 8>(lds, gA, gB, stq, aBase, bBase, kof0, kof1, acc);   // 124
  ktile<1, false, 8>(lds, gA, gB, stq, aBase, bBase, kof0, kof1, acc);  // 125
  ktile<2, false, 4>(lds, gA, gB, stq, aBase, bBase, kof0, kof1, acc);  // 126
  ktile<3, false, 0>(lds, gA, gB, stq, aBase, bBase, kof0, kof1, acc);  // 127

  // epilogue: 32x32 C/D layout col = lane&31, row = (reg&3) + 8*(reg>>2) + 4*(lane>>5)
#pragma unroll
  for (int nf = 0; nf < 2; ++nf) {
    const int gn = n0 + wc * 64 + nf * 32 + rl;
    const float bv = bias[gn];
#pragma unroll
    for (int mf = 0; mf < 4; ++mf) {
      const int base = m0 + wr * 128 + mf * 32 + 4 * hi;
#pragma unroll
      for (int q = 0; q < 4; ++q) {
        float* cp = C + (size_t)(base + 8 * q) * NDIM + gn;
#pragma unroll
        for (int rr = 0; rr < 4; ++rr)
          cp[(size_t)rr * NDIM] = acc[mf][nf][q * 4 + rr] + bv;
      }
    }
  }
}

extern "C" void kernel_launch(void* const* d_in, const int* in_sizes, int n_in,
                              void* d_out, int out_size, void* d_ws, size_t ws_size,
                              hipStream_t stream) {
  const float* inp  = (const float*)d_in[0];
  const float* bias = (const float*)d_in[1];
  const int* pw     = (const int*)d_in[2];
  const int* sc     = (const int*)d_in[3];
  float* out = (float*)d_out;

  unsigned short* a_bf = (unsigned short*)d_ws;
  unsigned short* w_bf = a_bf + (size_t)MDIM * KDIM;
  size_t need = ((size_t)MDIM * KDIM + (size_t)NDIM * KDIM) * sizeof(unsigned short);
  if (ws_size < need) return;

  prep_kernel<<<dim3(CONV_BLOCKS + DEQ_BLOCKS), dim3(256), 0, stream>>>(
      (const float4*)inp, (u16x8*)a_bf, pw, sc, w_bf);
  gemm_mx_kernel<<<dim3(NBX * NBY), dim3(512), 0, stream>>>(a_bf, w_bf, bias, out);
}

// Round 7
// 859.030 us; speedup vs baseline: 1.0547x; 1.0547x over previous
//
#include <hip/hip_runtime.h>
#include <stdint.h>

typedef __attribute__((ext_vector_type(8))) short bf16x8;
typedef __attribute__((ext_vector_type(8))) unsigned short u16x8;
typedef __attribute__((ext_vector_type(16))) float f32x16;
typedef __attribute__((ext_vector_type(4))) int i32x4;

static constexpr int MDIM = 8192;   // B*S
static constexpr int KDIM = 4096;   // I
static constexpr int NDIM = 11008;  // O
static constexpr int BM = 256, BN = 256, BK = 32;
static constexpr int NBX = NDIM / BN;  // 43
static constexpr int NBY = MDIM / BM;  // 32

// ---------------- prep: fused A-convert + W-dequant (verified R1/R2/R5/R6) ----------------

static __device__ __forceinline__ unsigned short f2bf(float f) {
  unsigned int u = __builtin_bit_cast(unsigned int, f);
  return (unsigned short)((u + 0x7FFFu + ((u >> 16) & 1u)) >> 16);
}

static __device__ __forceinline__ float fp4_val(unsigned int c) {
  unsigned int m = c & 1u, e = (c >> 1) & 3u, s = (c >> 3) & 1u;
  unsigned int bits = e ? (((126u + e) << 23) | (m << 22)) : (m ? 0x3F000000u : 0u);
  bits |= s << 31;
  return __builtin_bit_cast(float, bits);
}

static constexpr int CONV_BLOCKS = (MDIM * KDIM / 8) / 256;     // 16384
static constexpr int DEQ_BLOCKS  = (NDIM * (KDIM / 32)) / 256;  // 5504

__global__ __launch_bounds__(256) void prep_kernel(
    const float4* __restrict__ in, u16x8* __restrict__ aout,
    const int* __restrict__ pw, const int* __restrict__ sc,
    unsigned short* __restrict__ wout) {
  if (blockIdx.x < CONV_BLOCKS) {
    int i = blockIdx.x * 256 + threadIdx.x;
    float4 v0 = in[2 * (size_t)i];
    float4 v1 = in[2 * (size_t)i + 1];
    u16x8 r;
    r[0] = f2bf(v0.x); r[1] = f2bf(v0.y); r[2] = f2bf(v0.z); r[3] = f2bf(v0.w);
    r[4] = f2bf(v1.x); r[5] = f2bf(v1.y); r[6] = f2bf(v1.z); r[7] = f2bf(v1.w);
    aout[i] = r;
  } else {
    int tid = (blockIdx.x - CONV_BLOCKS) * 256 + threadIdx.x;
    int o = tid >> 7;
    int b = tid & 127;
    const i32x4* src = (const i32x4*)(pw + (size_t)o * (KDIM / 2) + b * 16);
    unsigned int e = (unsigned int)sc[(size_t)o * (KDIM / 32) + b];
    float scale = __builtin_bit_cast(float, e << 23);
    unsigned short* dst = wout + (size_t)o * KDIM + b * 32;
#pragma unroll
    for (int v = 0; v < 4; ++v) {
      i32x4 w4 = src[v];
      u16x8 r;
#pragma unroll
      for (int j = 0; j < 4; ++j) {
        unsigned int w = (unsigned int)w4[j];
        r[2 * j]     = f2bf(fp4_val(w & 0xFu) * scale);
        r[2 * j + 1] = f2bf(fp4_val((w >> 4) & 0xFu) * scale);
      }
      *(u16x8*)(dst + 8 * v) = r;
    }
  }
}

// ------- GEMM: 256x256, BK=32, 32x32x16 MFMA, 4-slot ring (3 ahead), 1 barrier/tile -------

#define GLDS16(gp, lp)                                                                  \
  __builtin_amdgcn_global_load_lds((const __attribute__((address_space(1))) void*)(gp), \
                                   (__attribute__((address_space(3))) void*)(lp), 16, 0, 0)

#define BAR() asm volatile("s_barrier" ::: "memory")

// One K-tile, slot = SLOT; stages tile (t+3) into slot (SLOT+3)&3.
// vmcnt ledger (4 loads/tile): entering tile t outstanding = {t,t+1,t+2} = 12;
// vmcnt(8) completes t's 4. Tail (no stage): t=125 -> 8, t=126 -> 4, t=127 -> 0.
template <int SLOT, bool STAGE, int VN>
__device__ __forceinline__ void ktile(
    unsigned char* lds, const unsigned short*& gA, const unsigned short*& gB,
    int stq, int aBase, int bBase, int kof0, int kof1, f32x16 (&acc)[4][2]) {
  if constexpr (VN == 8)      asm volatile("s_waitcnt vmcnt(8)" ::: "memory");
  else if constexpr (VN == 4) asm volatile("s_waitcnt vmcnt(4)" ::: "memory");
  else                        asm volatile("s_waitcnt vmcnt(0)" ::: "memory");
  BAR();
  if (STAGE) {
    unsigned char* da = lds + ((SLOT + 3) & 3) * 32768 + stq;
    GLDS16(gA, da);
    GLDS16(gA + (size_t)128 * KDIM, da + 8192);
    GLDS16(gB, da + 16384);
    GLDS16(gB + (size_t)128 * KDIM, da + 24576);
    gA += BK; gB += BK;
  }
  const unsigned char* sa = lds + SLOT * 32768;
  const unsigned char* sb = sa + 16384;
  bf16x8 a[4], b[2];
  // cluster ks=0
#pragma unroll
  for (int mf = 0; mf < 4; ++mf) a[mf] = *(const bf16x8*)(sa + aBase + mf * 2048 + kof0);
#pragma unroll
  for (int nf = 0; nf < 2; ++nf) b[nf] = *(const bf16x8*)(sb + bBase + nf * 2048 + kof0);
  __builtin_amdgcn_s_setprio(1);
#pragma unroll
  for (int mf = 0; mf < 4; ++mf)
#pragma unroll
    for (int nf = 0; nf < 2; ++nf)
      acc[mf][nf] = __builtin_amdgcn_mfma_f32_32x32x16_bf16(a[mf], b[nf], acc[mf][nf], 0, 0, 0);
  __builtin_amdgcn_s_setprio(0);
  // cluster ks=1
#pragma unroll
  for (int mf = 0; mf < 4; ++mf) a[mf] = *(const bf16x8*)(sa + aBase + mf * 2048 + kof1);
#pragma unroll
  for (int nf = 0; nf < 2; ++nf) b[nf] = *(const bf16x8*)(sb + bBase + nf * 2048 + kof1);
  __builtin_amdgcn_s_setprio(1);
#pragma unroll
  for (int mf = 0; mf < 4; ++mf)
#pragma unroll
    for (int nf = 0; nf < 2; ++nf)
      acc[mf][nf] = __builtin_amdgcn_mfma_f32_32x32x16_bf16(a[mf], b[nf], acc[mf][nf], 0, 0, 0);
  __builtin_amdgcn_s_setprio(0);
}

__global__ __launch_bounds__(512, 2) void gemm_mx_kernel(
    const unsigned short* __restrict__ A,   // [MDIM][KDIM] bf16
    const unsigned short* __restrict__ Bw,  // [NDIM][KDIM] bf16
    const float* __restrict__ bias,
    float* __restrict__ C) {
  __shared__ __align__(16) unsigned char lds[4 * 32768];  // 128 KiB: 4 x (A16K + B16K)

  const int t = threadIdx.x;
  const int lane = t & 63;
  const int wave = t >> 6;
  const int wr = wave >> 2;  // 0..1 (M)
  const int wc = wave & 3;   // 0..3 (N)

  // bijective XCD swizzle (grid 1376 % 8 == 0)
  const int bid = blockIdx.x;
  const int swb = (bid & 7) * ((NBX * NBY) / 8) + (bid >> 3);
  const int by = swb / NBX;
  const int bx = swb - by * NBX;
  const int m0 = by * BM, n0 = bx * BN;

  // 32x32x16 fragments: lane l holds row (l&31), k = (l>>5)*8 + r.
  const int rl = lane & 31;
  const int hi = lane >> 5;
  // Rows are 64 B (4 x 16B granules). Swizzle: granule' = (2*ks+hi) ^ ((row>>1)&3).
  // BUGFIX R6->R7: was ^(row&3) — its low bit duplicates the row-parity bank bit, so
  // the wave hit only 4 of 8 16B-slots per 128B bank cycle (2.03e8 conflicts, ~12
  // extra cyc/read). Using row bits [2:1] gives all 8 slots x 8 lanes uniform -> ~0.
  const int kof0 = ((0 + hi) ^ ((rl >> 1) & 3)) * 16;
  const int kof1 = ((2 + hi) ^ ((rl >> 1) & 3)) * 16;
  const int aBase = (wr * 128 + rl) * 64;  // frag stride mf: 32 rows = 2048 B
  const int bBase = (wc * 64 + rl) * 64;   // frag stride nf: 32 rows = 2048 B

  // staging: LDS linear; matching inverse swizzle on the global source column.
  // thread t writes LDS row (t>>2), granule (t&3); source granule = (t&3) ^ ((row>>1)&3)
  // with row = t>>2  ->  (t>>3)&3.   (all staging region bases are == 0 mod 32 rows)
  const int stq = t * 16;
  const int srow = t >> 2;                        // 0..127
  const int koff = 8 * ((t & 3) ^ ((t >> 3) & 3));  // element offset within row
  const unsigned short* gA = A + (size_t)(m0 + srow) * KDIM + koff;
  const unsigned short* gB = Bw + (size_t)(n0 + srow) * KDIM + koff;

  f32x16 acc[4][2] = {};

  // prologue: stage tiles 0,1,2 into slots 0,1,2 (12 loads in flight)
#pragma unroll
  for (int p = 0; p < 3; ++p) {
    unsigned char* da = lds + p * 32768 + stq;
    GLDS16(gA, da);
    GLDS16(gA + (size_t)128 * KDIM, da + 8192);
    GLDS16(gB, da + 16384);
    GLDS16(gB + (size_t)128 * KDIM, da + 24576);
    gA += BK; gB += BK;
  }

  // tiles 0..123 (31 x 4, all staging), 124 (stages 127), 125..127 (drain tail)
  for (int it = 0; it < 31; ++it) {
    ktile<0, true, 8>(lds, gA, gB, stq, aBase, bBase, kof0, kof1, acc);
    ktile<1, true, 8>(lds, gA, gB, stq, aBase, bBase, kof0, kof1, acc);
    ktile<2, true, 8>(lds, gA, gB, stq, aBase, bBase, kof0, kof1, acc);
    ktile<3, true, 8>(lds, gA, gB, stq, aBase, bBase, kof0, kof1, acc);
  }
  ktile<0, true, 8>(lds, gA, gB, stq, aBase, bBase, kof0, kof1, acc);   // 124
  ktile<1, false, 8>(lds, gA, gB, stq, aBase, bBase, kof0, kof1, acc);  // 125
  ktile<2, false, 4>(lds, gA, gB, stq, aBase, bBase, kof0, kof1, acc);  // 126
  ktile<3, false, 0>(lds, gA, gB, stq, aBase, bBase, kof0, kof1, acc);  // 127

  // epilogue: 32x32 C/D layout col = lane&31, row = (reg&3) + 8*(reg>>2) + 4*(lane>>5)
#pragma unroll
  for (int nf = 0; nf < 2; ++nf) {
    const int gn = n0 + wc * 64 + nf * 32 + rl;
    const float bv = bias[gn];
#pragma unroll
    for (int mf = 0; mf < 4; ++mf) {
      const int base = m0 + wr * 128 + mf * 32 + 4 * hi;
#pragma unroll
      for (int q = 0; q < 4; ++q) {
        float* cp = C + (size_t)(base + 8 * q) * NDIM + gn;
#pragma unroll
        for (int rr = 0; rr < 4; ++rr)
          cp[(size_t)rr * NDIM] = acc[mf][nf][q * 4 + rr] + bv;
      }
    }
  }
}

extern "C" void kernel_launch(void* const* d_in, const int* in_sizes, int n_in,
                              void* d_out, int out_size, void* d_ws, size_t ws_size,
                              hipStream_t stream) {
  const float* inp  = (const float*)d_in[0];
  const float* bias = (const float*)d_in[1];
  const int* pw     = (const int*)d_in[2];
  const int* sc     = (const int*)d_in[3];
  float* out = (float*)d_out;

  unsigned short* a_bf = (unsigned short*)d_ws;
  unsigned short* w_bf = a_bf + (size_t)MDIM * KDIM;
  size_t need = ((size_t)MDIM * KDIM + (size_t)NDIM * KDIM) * sizeof(unsigned short);
  if (ws_size < need) return;

  prep_kernel<<<dim3(CONV_BLOCKS + DEQ_BLOCKS), dim3(256), 0, stream>>>(
      (const float4*)inp, (u16x8*)a_bf, pw, sc, w_bf);
  gemm_mx_kernel<<<dim3(NBX * NBY), dim3(512), 0, stream>>>(a_bf, w_bf, bias, out);
}